// Round 10
// baseline (290.534 us; speedup 1.0000x reference)
//
#include <hip/hip_runtime.h>
#include <hip/hip_fp16.h>

#define HH 96
#define WW 96
#define CC 128

typedef float f32x4 __attribute__((ext_vector_type(4)));
typedef short short8 __attribute__((ext_vector_type(8)));
typedef _Float16 f16x8 __attribute__((ext_vector_type(8)));

union U32H2 { unsigned int u; __half2 h; };
__device__ __forceinline__ unsigned int pack2(float x, float y){ U32H2 t; t.h=__floats2half2_rn(x,y); return t.u; }

// truncating f32 pair -> bf16x2 pack, single v_perm (low16 = bf(lo), high16 = bf(hi))
__device__ __forceinline__ unsigned int pkbf_t(float lo, float hi){
  return __builtin_amdgcn_perm(__float_as_uint(hi), __float_as_uint(lo), 0x07060302u);
}

union U4S8 { uint4 q; short8 s; };
union U4H8 { uint4 q; f16x8 h; };

// -------------------------------------------------------------------------
// Kernel 1 (MFMA): cost volume, BARRIER-FREE / LDS-FREE.
// Evidence (rounds 4-9): dur ~105us invariant to occupancy, coalescing,
// and even HBM-vs-L3 residency (replay rows: FETCH~0, same dur) ->
// the barrier-locked stage/drain/compute pipeline exposes full memory
// latency 5x per block with ~1.6 blocks/CU. Fix: remove all sync.
// Each wave = one (y, dy-group of 3): loads A (prv) and B (nxt) fragments
// DIRECTLY from global in MFMA lane layout (A pattern proven in round 3),
// packs f32->bf16 with 1-instr truncating v_perm (RNE pkbf too expensive
// at direct-load redundancy; truncation shrinks dot ~0.8% rel, absmax
// stays well under threshold). acc[3][2] = 24 AGPR. No LDS, no barriers:
// 16 indep waves/CU hide latency. Blocks pack 8 consecutive y so L1
// absorbs the cross-y B-row overlap.
// Band extraction identical to round 8 (ch0 = dg*27).
// OOB rows/cols: clamped address + cndmask-zeroed fragment -> contributes
// exact 0 (matches reference zero padding).
// -------------------------------------------------------------------------
__global__ __launch_bounds__(512, 4) void k_cost_direct(const float* __restrict__ prv,
                                                        const float* __restrict__ nxt,
                                                        __half* __restrict__ cost) {
  const int x0 = (blockIdx.x % 6) * 16;
  const int dg = blockIdx.x / 6;        // dy-group: dy = dg*3 + d, d in 0..2
  const int y  = blockIdx.y * 8 + (threadIdx.x >> 6);
  const int b  = blockIdx.z;
  const int l  = threadIdx.x & 63;
  const int lm = l & 15, lq = l >> 4;

  // A pointer (always in-bounds): prv[y, x0+lm, lq*8 ...]
  const float* ap = &prv[((size_t)(b*HH + y)*WW + x0 + lm)*CC + lq*8];

  // B pointers for 3 dy x 2 n-tiles: nxt[y+dg*3+d-4, x0-4+t*16+lm, lq*8 ...]
  const float* bp[3][2];
  bool ok[3][2];
#pragma unroll
  for (int d = 0; d < 3; ++d) {
    const int row = y + dg*3 + d - 4;
    const int crow = row < 0 ? 0 : (row > HH-1 ? HH-1 : row);
#pragma unroll
    for (int t = 0; t < 2; ++t) {
      const int col = x0 - 4 + t*16 + lm;
      const int ccol = col < 0 ? 0 : (col > WW-1 ? WW-1 : col);
      ok[d][t] = ((unsigned)row < HH) && ((unsigned)col < WW);
      bp[d][t] = &nxt[((size_t)(b*HH + crow)*WW + ccol)*CC + lq*8];
    }
  }

  f32x4 acc[3][2];
#pragma unroll
  for (int d = 0; d < 3; ++d) {
    acc[d][0] = (f32x4){0.f,0.f,0.f,0.f};
    acc[d][1] = (f32x4){0.f,0.f,0.f,0.f};
  }

#pragma unroll 1
  for (int ks = 0; ks < 4; ++ks) {
    const int co = ks * 32;             // channel offset this K-step

    // A fragment
    const float4 a0 = *(const float4*)(ap + co);
    const float4 a1 = *(const float4*)(ap + co + 4);
    U4S8 af;
    af.q.x = pkbf_t(a0.x, a0.y); af.q.y = pkbf_t(a0.z, a0.w);
    af.q.z = pkbf_t(a1.x, a1.y); af.q.w = pkbf_t(a1.z, a1.w);

    // B fragments + MFMA
#pragma unroll
    for (int d = 0; d < 3; ++d) {
#pragma unroll
      for (int t = 0; t < 2; ++t) {
        const float4 b0 = *(const float4*)(bp[d][t] + co);
        const float4 b1 = *(const float4*)(bp[d][t] + co + 4);
        U4S8 bf;
        bf.q.x = ok[d][t] ? pkbf_t(b0.x, b0.y) : 0u;
        bf.q.y = ok[d][t] ? pkbf_t(b0.z, b0.w) : 0u;
        bf.q.z = ok[d][t] ? pkbf_t(b1.x, b1.y) : 0u;
        bf.q.w = ok[d][t] ? pkbf_t(b1.z, b1.w) : 0u;
        acc[d][t] = __builtin_amdgcn_mfma_f32_16x16x32_bf16(af.s, bf.s, acc[d][t], 0, 0, 0);
      }
    }
  }

  // band extraction: lane holds C[m=lq*4+reg][p=t*16+lm]; od = p - m
  const int ch0 = dg*27;                // dy = dg*3+d -> channel dg*27 + d*9 + od
#pragma unroll
  for (int t = 0; t < 2; ++t) {
#pragma unroll
    for (int reg = 0; reg < 4; ++reg) {
      const int m  = lq*4 + reg;
      const int od = t*16 + lm - m;
      if (od >= 0 && od <= 8) {
        __half* cbp = &cost[((size_t)(b*HH + y)*WW + x0 + m)*96 + ch0 + od];
#pragma unroll
        for (int d = 0; d < 3; ++d) {
          float v = acc[d][t][reg] * 0.0078125f;
          v = (v >= 0.f) ? v : 0.1f * v;
          cbp[d*9] = __float2half(v);
        }
      }
    }
  }
}

// -------------------------------------------------------------------------
// Kernel 2 (MFMA): conv as GEMM + gather.  (unchanged from round 4)
// G[px, j=tap*2+n] = sum_k feat[px,k] * W[tap,k,n]   (M=324, K=352, N=18->32)
// out[y,x,n] = cb[n] + sum_tap G[y+dy-1, x+dx-1, tap*2+n]
// -------------------------------------------------------------------------
__global__ __launch_bounds__(512) void k_conv_gemm(const float* __restrict__ prv,
                                                   const float* __restrict__ nxt,
                                                   const __half* __restrict__ cost,
                                                   const float* __restrict__ cw,
                                                   const float* __restrict__ cb,
                                                   float* __restrict__ out) {
  const int tw0 = blockIdx.x*16, th0 = blockIdx.y*16, b = blockIdx.z;
  const int tid = threadIdx.x;
  const int w = tid >> 6, l = tid & 63;
  const int lm = l & 15, lq = l >> 4;

  __shared__ __align__(16) char smem[49408];
  uint4*        feat16 = (uint4*)smem;               // [336 px][40 half]
  float*        Gf     = (float*)smem;               // [324][20] f32 (aliased)
  float2*       Gf2    = (float2*)smem;
  uint4*        B2     = (uint4*)(smem + 26880);     // [(kc*4+lq)*32 + j]
  __half*       B2h    = (__half*)(smem + 26880);

#pragma unroll 1
  for (int i = tid; i < 5632; i += 512) ((unsigned int*)B2)[i] = 0u;
#pragma unroll 1
  for (int i = tid; i < 240; i += 512) ((unsigned int*)smem)[6480 + i] = 0u;
#pragma unroll 1
  for (int i = tid; i < 352*18; i += 512) {
    const int ci = i / 18, j = i - 18*ci;
    if (ci >= 81 && ci < 96) continue;
    const int wci = (ci < 81) ? ci : ci - 15;
    const int tap = j >> 1, n = j & 1;
    const float v = cw[(tap*337 + wci)*2 + n];
    const int kk = ci & 31;
    B2h[((((ci >> 5)*4 + (kk >> 3))*32) + j)*8 + (kk & 7)] = __float2half(v);
  }

  f32x4 acc[3][2];
#pragma unroll
  for (int i = 0; i < 3; ++i) { acc[i][0] = (f32x4){0,0,0,0}; acc[i][1] = (f32x4){0,0,0,0}; }

#pragma unroll 1
  for (int kc = 0; kc < 11; ++kc) {
    __syncthreads();
#pragma unroll 1
    for (int i = tid; i < 648; i += 512) {
      const int px = i >> 1, half = i & 1;
      const int hr = px / 18, hc = px - 18*hr;
      const int gr = th0 - 1 + hr, gc = tw0 - 1 + hc;
      uint4 d0 = make_uint4(0,0,0,0), d1 = make_uint4(0,0,0,0);
      if ((unsigned)gr < HH && (unsigned)gc < WW) {
        const size_t pixi = (size_t)(b*HH + gr)*WW + gc;
        if (kc < 3) {
          const uint4* cs = (const uint4*)&cost[pixi*96 + kc*32 + half*16];
          d0 = cs[0]; d1 = cs[1];
        } else {
          const float* src = (kc < 7) ? prv : nxt;
          const int c0 = ((kc < 7) ? (kc-3) : (kc-7))*32 + half*16;
          const float4 f0 = *(const float4*)&src[pixi*128 + c0];
          const float4 f1 = *(const float4*)&src[pixi*128 + c0 + 4];
          const float4 f2 = *(const float4*)&src[pixi*128 + c0 + 8];
          const float4 f3 = *(const float4*)&src[pixi*128 + c0 + 12];
          d0 = make_uint4(pack2(f0.x,f0.y), pack2(f0.z,f0.w), pack2(f1.x,f1.y), pack2(f1.z,f1.w));
          d1 = make_uint4(pack2(f2.x,f2.y), pack2(f2.z,f2.w), pack2(f3.x,f3.y), pack2(f3.z,f3.w));
        }
      }
      feat16[5*px + 2*half]     = d0;
      feat16[5*px + 2*half + 1] = d1;
    }
    __syncthreads();

    U4H8 bf0, bf1;
    bf0.q = B2[(kc*4 + lq)*32 + lm];
    bf1.q = B2[(kc*4 + lq)*32 + 16 + lm];
#pragma unroll
    for (int i = 0; i < 3; ++i) {
      const int mf = w + 8*i;
      if (mf < 21) {
        U4H8 af;
        af.q = feat16[5*(16*mf + lm) + lq];
        acc[i][0] = __builtin_amdgcn_mfma_f32_16x16x32_f16(af.h, bf0.h, acc[i][0], 0, 0, 0);
        acc[i][1] = __builtin_amdgcn_mfma_f32_16x16x32_f16(af.h, bf1.h, acc[i][1], 0, 0, 0);
      }
    }
  }
  __syncthreads();

#pragma unroll
  for (int i = 0; i < 3; ++i) {
    const int mf = w + 8*i;
    if (mf >= 21) continue;
#pragma unroll
    for (int r = 0; r < 4; ++r) {
      const int px = 16*mf + lq*4 + r;
      if (px < 324) {
        Gf[px*20 + lm] = acc[i][0][r];
        if (lm < 2) Gf[px*20 + 16 + lm] = acc[i][1][r];
      }
    }
  }
  __syncthreads();

  if (tid < 512) {
    const int px = tid >> 1, n = tid & 1;
    const int ty = px >> 4, tx = px & 15;
    float s = cb[n];
#pragma unroll
    for (int p = 0; p < 9; ++p) {
      const int dy = p / 3, dx = p - 3*dy;
      const int hp = (ty + dy)*18 + (tx + dx);
      const float2 g = Gf2[hp*10 + p];
      s += n ? g.y : g.x;
    }
    out[((size_t)(b*HH + th0 + ty)*WW + (tw0 + tx))*2 + n] = s;
  }
}

extern "C" void kernel_launch(void* const* d_in, const int* in_sizes, int n_in,
                              void* d_out, int out_size, void* d_ws, size_t ws_size,
                              hipStream_t stream) {
  const float* prv = (const float*)d_in[0];
  const float* nxt = (const float*)d_in[1];
  const float* cw  = (const float*)d_in[2];
  const float* cb  = (const float*)d_in[3];
  __half* cost = (__half*)d_ws;   // 16*96*96*96*2 = 28,311,552 bytes

  k_cost_direct<<<dim3(18, 12, 16), dim3(512), 0, stream>>>(prv, nxt, cost);
  k_conv_gemm<<<dim3(6, 6, 16), dim3(512), 0, stream>>>(prv, nxt, cost, cw, cb, (float*)d_out);
}

// Round 11
// 118.850 us; speedup vs baseline: 2.4445x; 2.4445x over previous
//
#include <hip/hip_runtime.h>
#include <hip/hip_fp16.h>

#define HH 96
#define WW 96
#define CC 128

#define RS 25   // ntile row stride (uint4 slots), padded 24->25 for bank spread
#define PS 17   // ptile row stride, padded 16->17

typedef float f32x4 __attribute__((ext_vector_type(4)));
typedef _Float16 f16x8 __attribute__((ext_vector_type(8)));

union U32H2 { unsigned int u; __half2 h; };
__device__ __forceinline__ unsigned int pack2(float x, float y){ U32H2 t; t.h=__floats2half2_rn(x,y); return t.u; }

union U4H8 { uint4 q; f16x8 h; };

// -------------------------------------------------------------------------
// Kernel 0: one-time f32 -> f16 conversion of prv & nxt into workspace.
// Pure stream (read 151MB f32, write 75.5MB f16). Paid once; halves the
// lane-load count of BOTH downstream kernels (dur has tracked lane-load
// count across rounds 4-10) and deletes all f32->f16 pack VALU from them.
// -------------------------------------------------------------------------
__global__ __launch_bounds__(256) void k_convert(const float* __restrict__ prv,
                                                 const float* __restrict__ nxt,
                                                 uint2* __restrict__ prv_h,
                                                 uint2* __restrict__ nxt_h) {
  const float4* src = (const float4*)(blockIdx.z ? nxt : prv);
  uint2* dst = blockIdx.z ? nxt_h : prv_h;
  const int total = 16*HH*WW*CC/4;     // float4 units
  for (int i = blockIdx.x*256 + threadIdx.x; i < total; i += gridDim.x*256) {
    const float4 f = src[i];
    uint2 d; d.x = pack2(f.x, f.y); d.y = pack2(f.z, f.w);
    dst[i] = d;
  }
}

// MMA inner step for a dy-range (wave-uniform template), f16 fragments
template<int DY0, int NDY>
static __device__ __forceinline__ void cost_mma(const uint4* __restrict__ nt,
                                                int yr, int lq, int lm,
                                                f16x8 a, f32x4 (&acc)[5][2]) {
#pragma unroll
  for (int d = 0; d < NDY; ++d) {
    const int sb = ((yr + DY0 + d)*4 + lq)*RS;
    U4H8 b0, b1;
    b0.q = nt[sb + lm];
    b1.q = nt[sb + 16 + lm];
    acc[d][0] = __builtin_amdgcn_mfma_f32_16x16x32_f16(a, b0.h, acc[d][0], 0, 0, 0);
    acc[d][1] = __builtin_amdgcn_mfma_f32_16x16x32_f16(a, b1.h, acc[d][1], 0, 0, 0);
  }
}

// -------------------------------------------------------------------------
// Kernel 1 (MFMA): cost volume via banded GEMM, f16 inputs.
// Round-11 = round-6 structure (T=4 y-rows, 8 waves = 4y x 2 dy-halves,
// acc[5][2]=40 regs, proven MFMA/extraction indexing) with:
//  - staging = RAW uint4 copies from pre-converted f16 (1152+256 lane-loads
//    per K-step vs 2304+512 f32; zero pack VALU; in-flight staging regs
//    drop from ~32 to ~4)
//  - __launch_bounds__(512, 6): <=85 unified regs -> 3 blocks/CU (24 waves,
//    75%) vs round-6's 2 (43% measured). k_conv at 3 blocks/CU runs 3x the
//    slot-rate of k_cost; this is the occupancy experiment.
// Adjudicators: VGPR_Count<=85 & WRITE_SIZE~28MB => no spill; occupancy.
// ntile t=1 overrun reads feed only od>8 never-extracted band positions
// (C columns independent under MFMA) - proven rounds 4-10.
// -------------------------------------------------------------------------
__global__ __launch_bounds__(512, 6) void k_cost_mfma(const uint4* __restrict__ prv_h,
                                                      const uint4* __restrict__ nxt_h,
                                                      __half* __restrict__ cost) {
  const int x0 = blockIdx.x * 16;
  const int y0 = blockIdx.y * 4;       // 4 output rows per block
  const int b  = blockIdx.z;
  const int tid = threadIdx.x;
  const int w = tid >> 6, l = tid & 63;
  const int lm = l & 15, lq = l >> 4;
  const int yr = w >> 1, hf = w & 1;   // y-row 0..3, dy-half
  const int y = y0 + yr;

  __shared__ uint4 ntile[2][1232];     // [(r*4+c4)*25 + p], r 0..11, p 0..23 (+overrun)
  __shared__ uint4 ptile[2][272];      // [(row*4+c4)*17 + px]

  f32x4 acc[5][2];
#pragma unroll
  for (int d = 0; d < 5; ++d) {
    acc[d][0] = (f32x4){0.f,0.f,0.f,0.f};
    acc[d][1] = (f32x4){0.f,0.f,0.f,0.f};
  }

  // nxt staging map (hoisted): s in [0,1152): px = s>>2, c4 = s&3
  // one uint4 = 8 f16 channels; px layout 12 rows x 24 cols
  // prv staging map: tid<256: row=tid>>6, c4=(tid>>4)&3, col=tid&15
  const int p_row = tid >> 6, p_c4 = (tid >> 4) & 3, p_col = tid & 15;
  const size_t p_base = ((size_t)(b*HH + y0 + p_row)*WW + x0 + p_col)*16; // uint4 units (256B/px)

  auto stage = [&](int ks, int buf){
#pragma unroll
    for (int j = 0; j < 3; ++j) {
      const int s = j*512 + tid;
      if (s < 1152) {
        const int px = s >> 2, c4 = s & 3;
        const int row = px / 24, col = px - 24*row;
        const int gr = y0 - 4 + row, gc = x0 - 4 + col;
        uint4 d = make_uint4(0u,0u,0u,0u);
        if ((unsigned)gr < HH && (unsigned)gc < WW)
          d = nxt_h[((size_t)(b*HH + gr)*WW + gc)*16 + ks*4 + c4];
        ntile[buf][(row*4 + c4)*RS + col] = d;
      }
    }
    if (tid < 256)
      ptile[buf][(p_row*4 + p_c4)*PS + p_col] = prv_h[p_base + ks*4 + p_c4];
  };

  stage(0, 0);

#pragma unroll 1
  for (int ks = 0; ks < 4; ++ks) {
    __syncthreads();                    // buf[ks&1] ready; buf^1 free
    if (ks < 3) stage(ks + 1, (ks + 1) & 1);

    const int cur = ks & 1;
    U4H8 af;
    af.q = ptile[cur][(yr*4 + lq)*PS + lm];   // A[m=lm][k=lq*8+j]
    const uint4* nt = ntile[cur];
    if (hf == 0) cost_mma<0,5>(nt, yr, lq, lm, af.h, acc);
    else         cost_mma<5,4>(nt, yr, lq, lm, af.h, acc);
  }

  // band extraction: lane holds C[m=lq*4+reg][p=t*16+lm]; od = p - m
  const int DY0 = hf ? 5 : 0, NDY = hf ? 4 : 5;
#pragma unroll
  for (int t = 0; t < 2; ++t) {
#pragma unroll
    for (int reg = 0; reg < 4; ++reg) {
      const int m  = lq*4 + reg;
      const int od = t*16 + lm - m;
      if (od >= 0 && od <= 8) {
        __half* bp = &cost[((size_t)(b*HH + y)*WW + x0 + m)*96 + DY0*9 + od];
#pragma unroll
        for (int d = 0; d < 5; ++d) {
          if (d < NDY) {                // wave-uniform guard
            float v = acc[d][t][reg] * 0.0078125f;
            v = (v >= 0.f) ? v : 0.1f * v;
            bp[d*9] = __float2half(v);
          }
        }
      }
    }
  }
}

// -------------------------------------------------------------------------
// Kernel 2 (MFMA): conv as GEMM + gather (round-4 structure; staging now
// reads f16 prv/nxt copies -> uniform 2-uint4 loads, no pack VALU).
// G[px, j=tap*2+n] = sum_k feat[px,k] * W[tap,k,n]   (M=324, K=352, N=18->32)
// out[y,x,n] = cb[n] + sum_tap G[y+dy-1, x+dx-1, tap*2+n]
// -------------------------------------------------------------------------
__global__ __launch_bounds__(512) void k_conv_gemm(const __half* __restrict__ prv_h,
                                                   const __half* __restrict__ nxt_h,
                                                   const __half* __restrict__ cost,
                                                   const float* __restrict__ cw,
                                                   const float* __restrict__ cb,
                                                   float* __restrict__ out) {
  const int tw0 = blockIdx.x*16, th0 = blockIdx.y*16, b = blockIdx.z;
  const int tid = threadIdx.x;
  const int w = tid >> 6, l = tid & 63;
  const int lm = l & 15, lq = l >> 4;

  __shared__ __align__(16) char smem[49408];
  uint4*        feat16 = (uint4*)smem;               // [336 px][40 half]
  float*        Gf     = (float*)smem;               // [324][20] f32 (aliased)
  float2*       Gf2    = (float2*)smem;
  uint4*        B2     = (uint4*)(smem + 26880);     // [(kc*4+lq)*32 + j]
  __half*       B2h    = (__half*)(smem + 26880);

#pragma unroll 1
  for (int i = tid; i < 5632; i += 512) ((unsigned int*)B2)[i] = 0u;
#pragma unroll 1
  for (int i = tid; i < 240; i += 512) ((unsigned int*)smem)[6480 + i] = 0u;
#pragma unroll 1
  for (int i = tid; i < 352*18; i += 512) {
    const int ci = i / 18, j = i - 18*ci;
    if (ci >= 81 && ci < 96) continue;
    const int wci = (ci < 81) ? ci : ci - 15;
    const int tap = j >> 1, n = j & 1;
    const float v = cw[(tap*337 + wci)*2 + n];
    const int kk = ci & 31;
    B2h[((((ci >> 5)*4 + (kk >> 3))*32) + j)*8 + (kk & 7)] = __float2half(v);
  }

  f32x4 acc[3][2];
#pragma unroll
  for (int i = 0; i < 3; ++i) { acc[i][0] = (f32x4){0,0,0,0}; acc[i][1] = (f32x4){0,0,0,0}; }

#pragma unroll 1
  for (int kc = 0; kc < 11; ++kc) {
    __syncthreads();
#pragma unroll 1
    for (int i = tid; i < 648; i += 512) {
      const int px = i >> 1, half = i & 1;
      const int hr = px / 18, hc = px - 18*hr;
      const int gr = th0 - 1 + hr, gc = tw0 - 1 + hc;
      uint4 d0 = make_uint4(0,0,0,0), d1 = make_uint4(0,0,0,0);
      if ((unsigned)gr < HH && (unsigned)gc < WW) {
        const size_t pixi = (size_t)(b*HH + gr)*WW + gc;
        const unsigned short* sp;
        if (kc < 3)      sp = (const unsigned short*)cost  + pixi*96  + kc*32 + half*16;
        else if (kc < 7) sp = (const unsigned short*)prv_h + pixi*128 + (kc-3)*32 + half*16;
        else             sp = (const unsigned short*)nxt_h + pixi*128 + (kc-7)*32 + half*16;
        const uint4* q = (const uint4*)sp;
        d0 = q[0]; d1 = q[1];
      }
      feat16[5*px + 2*half]     = d0;
      feat16[5*px + 2*half + 1] = d1;
    }
    __syncthreads();

    U4H8 bf0, bf1;
    bf0.q = B2[(kc*4 + lq)*32 + lm];
    bf1.q = B2[(kc*4 + lq)*32 + 16 + lm];
#pragma unroll
    for (int i = 0; i < 3; ++i) {
      const int mf = w + 8*i;
      if (mf < 21) {
        U4H8 af;
        af.q = feat16[5*(16*mf + lm) + lq];
        acc[i][0] = __builtin_amdgcn_mfma_f32_16x16x32_f16(af.h, bf0.h, acc[i][0], 0, 0, 0);
        acc[i][1] = __builtin_amdgcn_mfma_f32_16x16x32_f16(af.h, bf1.h, acc[i][1], 0, 0, 0);
      }
    }
  }
  __syncthreads();

#pragma unroll
  for (int i = 0; i < 3; ++i) {
    const int mf = w + 8*i;
    if (mf >= 21) continue;
#pragma unroll
    for (int r = 0; r < 4; ++r) {
      const int px = 16*mf + lq*4 + r;
      if (px < 324) {
        Gf[px*20 + lm] = acc[i][0][r];
        if (lm < 2) Gf[px*20 + 16 + lm] = acc[i][1][r];
      }
    }
  }
  __syncthreads();

  if (tid < 512) {
    const int px = tid >> 1, n = tid & 1;
    const int ty = px >> 4, tx = px & 15;
    float s = cb[n];
#pragma unroll
    for (int p = 0; p < 9; ++p) {
      const int dy = p / 3, dx = p - 3*dy;
      const int hp = (ty + dy)*18 + (tx + dx);
      const float2 g = Gf2[hp*10 + p];
      s += n ? g.y : g.x;
    }
    out[((size_t)(b*HH + th0 + ty)*WW + (tw0 + tx))*2 + n] = s;
  }
}

extern "C" void kernel_launch(void* const* d_in, const int* in_sizes, int n_in,
                              void* d_out, int out_size, void* d_ws, size_t ws_size,
                              hipStream_t stream) {
  const float* prv = (const float*)d_in[0];
  const float* nxt = (const float*)d_in[1];
  const float* cw  = (const float*)d_in[2];
  const float* cb  = (const float*)d_in[3];

  // ws layout: cost f16 [0, 28311552) | prv_h [28311552, +37748736) | nxt_h [...]
  char* wsb = (char*)d_ws;
  __half* cost  = (__half*)wsb;
  __half* prv_h = (__half*)(wsb + 28311552);
  __half* nxt_h = (__half*)(wsb + 28311552 + 37748736);

  k_convert<<<dim3(1024, 1, 2), dim3(256), 0, stream>>>(prv, nxt, (uint2*)prv_h, (uint2*)nxt_h);
  k_cost_mfma<<<dim3(6, 24, 16), dim3(512), 0, stream>>>((const uint4*)prv_h, (const uint4*)nxt_h, cost);
  k_conv_gemm<<<dim3(6, 6, 16), dim3(512), 0, stream>>>(prv_h, nxt_h, cost, cw, cb, (float*)d_out);
}

// Round 12
// 116.842 us; speedup vs baseline: 2.4865x; 1.0172x over previous
//
#include <hip/hip_runtime.h>
#include <hip/hip_fp16.h>

#define HH 96
#define WW 96
#define CC 128

#define RS 25   // ntile row stride (uint4 slots), padded 24->25 for bank spread
#define PS 17   // ptile row stride, padded 16->17

typedef float f32x4 __attribute__((ext_vector_type(4)));
typedef _Float16 f16x8 __attribute__((ext_vector_type(8)));

union U32H2 { unsigned int u; __half2 h; };
__device__ __forceinline__ unsigned int pack2(float x, float y){ U32H2 t; t.h=__floats2half2_rn(x,y); return t.u; }

union U4H8 { uint4 q; f16x8 h; };

// -------------------------------------------------------------------------
// Kernel 0: one-time f32 -> f16 conversion of prv & nxt into workspace.
// Round-12 fix: round-11's grid-stride loop had ONE dependent load in
// flight per wave (load->pack->store serialized; hipcc doesn't pipeline
// dynamic-trip loops) -> 2.3 TB/s, 65us, VALUBusy 2.3%. New: flat exact
// sizing, each thread issues 4 INDEPENDENT coalesced float4 loads
// (base, +256, +512, +768) then 4 uint2 stores -> 4x in-flight bytes.
// 4,718,592 float4 units per tensor = 1024/block x 4608 blocks exactly.
// -------------------------------------------------------------------------
__global__ __launch_bounds__(256) void k_convert(const float4* __restrict__ prv,
                                                 const float4* __restrict__ nxt,
                                                 uint2* __restrict__ prv_h,
                                                 uint2* __restrict__ nxt_h) {
  const float4* __restrict__ src = blockIdx.z ? nxt : prv;
  uint2* __restrict__ dst = blockIdx.z ? nxt_h : prv_h;
  const size_t base = (size_t)blockIdx.x * 1024 + threadIdx.x;
  const float4 a0 = src[base];
  const float4 a1 = src[base + 256];
  const float4 a2 = src[base + 512];
  const float4 a3 = src[base + 768];
  uint2 d0, d1, d2, d3;
  d0.x = pack2(a0.x, a0.y); d0.y = pack2(a0.z, a0.w);
  d1.x = pack2(a1.x, a1.y); d1.y = pack2(a1.z, a1.w);
  d2.x = pack2(a2.x, a2.y); d2.y = pack2(a2.z, a2.w);
  d3.x = pack2(a3.x, a3.y); d3.y = pack2(a3.z, a3.w);
  dst[base]       = d0;
  dst[base + 256] = d1;
  dst[base + 512] = d2;
  dst[base + 768] = d3;
}

// MMA inner step for a dy-range (wave-uniform template), f16 fragments
template<int DY0, int NDY>
static __device__ __forceinline__ void cost_mma(const uint4* __restrict__ nt,
                                                int yr, int lq, int lm,
                                                f16x8 a, f32x4 (&acc)[5][2]) {
#pragma unroll
  for (int d = 0; d < NDY; ++d) {
    const int sb = ((yr + DY0 + d)*4 + lq)*RS;
    U4H8 b0, b1;
    b0.q = nt[sb + lm];
    b1.q = nt[sb + 16 + lm];
    acc[d][0] = __builtin_amdgcn_mfma_f32_16x16x32_f16(a, b0.h, acc[d][0], 0, 0, 0);
    acc[d][1] = __builtin_amdgcn_mfma_f32_16x16x32_f16(a, b1.h, acc[d][1], 0, 0, 0);
  }
}

// -------------------------------------------------------------------------
// Kernel 1 (MFMA): cost volume via banded GEMM, f16 inputs.
// (unchanged from round 11 — it dropped out of the top-5 there)
// -------------------------------------------------------------------------
__global__ __launch_bounds__(512, 6) void k_cost_mfma(const uint4* __restrict__ prv_h,
                                                      const uint4* __restrict__ nxt_h,
                                                      __half* __restrict__ cost) {
  const int x0 = blockIdx.x * 16;
  const int y0 = blockIdx.y * 4;       // 4 output rows per block
  const int b  = blockIdx.z;
  const int tid = threadIdx.x;
  const int w = tid >> 6, l = tid & 63;
  const int lm = l & 15, lq = l >> 4;
  const int yr = w >> 1, hf = w & 1;   // y-row 0..3, dy-half
  const int y = y0 + yr;

  __shared__ uint4 ntile[2][1232];     // [(r*4+c4)*25 + p], r 0..11, p 0..23 (+overrun)
  __shared__ uint4 ptile[2][272];      // [(row*4+c4)*17 + px]

  f32x4 acc[5][2];
#pragma unroll
  for (int d = 0; d < 5; ++d) {
    acc[d][0] = (f32x4){0.f,0.f,0.f,0.f};
    acc[d][1] = (f32x4){0.f,0.f,0.f,0.f};
  }

  const int p_row = tid >> 6, p_c4 = (tid >> 4) & 3, p_col = tid & 15;
  const size_t p_base = ((size_t)(b*HH + y0 + p_row)*WW + x0 + p_col)*16; // uint4 units

  auto stage = [&](int ks, int buf){
#pragma unroll
    for (int j = 0; j < 3; ++j) {
      const int s = j*512 + tid;
      if (s < 1152) {
        const int px = s >> 2, c4 = s & 3;
        const int row = px / 24, col = px - 24*row;
        const int gr = y0 - 4 + row, gc = x0 - 4 + col;
        uint4 d = make_uint4(0u,0u,0u,0u);
        if ((unsigned)gr < HH && (unsigned)gc < WW)
          d = nxt_h[((size_t)(b*HH + gr)*WW + gc)*16 + ks*4 + c4];
        ntile[buf][(row*4 + c4)*RS + col] = d;
      }
    }
    if (tid < 256)
      ptile[buf][(p_row*4 + p_c4)*PS + p_col] = prv_h[p_base + ks*4 + p_c4];
  };

  stage(0, 0);

#pragma unroll 1
  for (int ks = 0; ks < 4; ++ks) {
    __syncthreads();                    // buf[ks&1] ready; buf^1 free
    if (ks < 3) stage(ks + 1, (ks + 1) & 1);

    const int cur = ks & 1;
    U4H8 af;
    af.q = ptile[cur][(yr*4 + lq)*PS + lm];   // A[m=lm][k=lq*8+j]
    const uint4* nt = ntile[cur];
    if (hf == 0) cost_mma<0,5>(nt, yr, lq, lm, af.h, acc);
    else         cost_mma<5,4>(nt, yr, lq, lm, af.h, acc);
  }

  // band extraction: lane holds C[m=lq*4+reg][p=t*16+lm]; od = p - m
  const int DY0 = hf ? 5 : 0, NDY = hf ? 4 : 5;
#pragma unroll
  for (int t = 0; t < 2; ++t) {
#pragma unroll
    for (int reg = 0; reg < 4; ++reg) {
      const int m  = lq*4 + reg;
      const int od = t*16 + lm - m;
      if (od >= 0 && od <= 8) {
        __half* bp = &cost[((size_t)(b*HH + y)*WW + x0 + m)*96 + DY0*9 + od];
#pragma unroll
        for (int d = 0; d < 5; ++d) {
          if (d < NDY) {                // wave-uniform guard
            float v = acc[d][t][reg] * 0.0078125f;
            v = (v >= 0.f) ? v : 0.1f * v;
            bp[d*9] = __float2half(v);
          }
        }
      }
    }
  }
}

// -------------------------------------------------------------------------
// Kernel 2 (MFMA): conv as GEMM + gather (unchanged from round 11).
// -------------------------------------------------------------------------
__global__ __launch_bounds__(512) void k_conv_gemm(const __half* __restrict__ prv_h,
                                                   const __half* __restrict__ nxt_h,
                                                   const __half* __restrict__ cost,
                                                   const float* __restrict__ cw,
                                                   const float* __restrict__ cb,
                                                   float* __restrict__ out) {
  const int tw0 = blockIdx.x*16, th0 = blockIdx.y*16, b = blockIdx.z;
  const int tid = threadIdx.x;
  const int w = tid >> 6, l = tid & 63;
  const int lm = l & 15, lq = l >> 4;

  __shared__ __align__(16) char smem[49408];
  uint4*        feat16 = (uint4*)smem;               // [336 px][40 half]
  float*        Gf     = (float*)smem;               // [324][20] f32 (aliased)
  float2*       Gf2    = (float2*)smem;
  uint4*        B2     = (uint4*)(smem + 26880);     // [(kc*4+lq)*32 + j]
  __half*       B2h    = (__half*)(smem + 26880);

#pragma unroll 1
  for (int i = tid; i < 5632; i += 512) ((unsigned int*)B2)[i] = 0u;
#pragma unroll 1
  for (int i = tid; i < 240; i += 512) ((unsigned int*)smem)[6480 + i] = 0u;
#pragma unroll 1
  for (int i = tid; i < 352*18; i += 512) {
    const int ci = i / 18, j = i - 18*ci;
    if (ci >= 81 && ci < 96) continue;
    const int wci = (ci < 81) ? ci : ci - 15;
    const int tap = j >> 1, n = j & 1;
    const float v = cw[(tap*337 + wci)*2 + n];
    const int kk = ci & 31;
    B2h[((((ci >> 5)*4 + (kk >> 3))*32) + j)*8 + (kk & 7)] = __float2half(v);
  }

  f32x4 acc[3][2];
#pragma unroll
  for (int i = 0; i < 3; ++i) { acc[i][0] = (f32x4){0,0,0,0}; acc[i][1] = (f32x4){0,0,0,0}; }

#pragma unroll 1
  for (int kc = 0; kc < 11; ++kc) {
    __syncthreads();
#pragma unroll 1
    for (int i = tid; i < 648; i += 512) {
      const int px = i >> 1, half = i & 1;
      const int hr = px / 18, hc = px - 18*hr;
      const int gr = th0 - 1 + hr, gc = tw0 - 1 + hc;
      uint4 d0 = make_uint4(0,0,0,0), d1 = make_uint4(0,0,0,0);
      if ((unsigned)gr < HH && (unsigned)gc < WW) {
        const size_t pixi = (size_t)(b*HH + gr)*WW + gc;
        const unsigned short* sp;
        if (kc < 3)      sp = (const unsigned short*)cost  + pixi*96  + kc*32 + half*16;
        else if (kc < 7) sp = (const unsigned short*)prv_h + pixi*128 + (kc-3)*32 + half*16;
        else             sp = (const unsigned short*)nxt_h + pixi*128 + (kc-7)*32 + half*16;
        const uint4* q = (const uint4*)sp;
        d0 = q[0]; d1 = q[1];
      }
      feat16[5*px + 2*half]     = d0;
      feat16[5*px + 2*half + 1] = d1;
    }
    __syncthreads();

    U4H8 bf0, bf1;
    bf0.q = B2[(kc*4 + lq)*32 + lm];
    bf1.q = B2[(kc*4 + lq)*32 + 16 + lm];
#pragma unroll
    for (int i = 0; i < 3; ++i) {
      const int mf = w + 8*i;
      if (mf < 21) {
        U4H8 af;
        af.q = feat16[5*(16*mf + lm) + lq];
        acc[i][0] = __builtin_amdgcn_mfma_f32_16x16x32_f16(af.h, bf0.h, acc[i][0], 0, 0, 0);
        acc[i][1] = __builtin_amdgcn_mfma_f32_16x16x32_f16(af.h, bf1.h, acc[i][1], 0, 0, 0);
      }
    }
  }
  __syncthreads();

#pragma unroll
  for (int i = 0; i < 3; ++i) {
    const int mf = w + 8*i;
    if (mf >= 21) continue;
#pragma unroll
    for (int r = 0; r < 4; ++r) {
      const int px = 16*mf + lq*4 + r;
      if (px < 324) {
        Gf[px*20 + lm] = acc[i][0][r];
        if (lm < 2) Gf[px*20 + 16 + lm] = acc[i][1][r];
      }
    }
  }
  __syncthreads();

  if (tid < 512) {
    const int px = tid >> 1, n = tid & 1;
    const int ty = px >> 4, tx = px & 15;
    float s = cb[n];
#pragma unroll
    for (int p = 0; p < 9; ++p) {
      const int dy = p / 3, dx = p - 3*dy;
      const int hp = (ty + dy)*18 + (tx + dx);
      const float2 g = Gf2[hp*10 + p];
      s += n ? g.y : g.x;
    }
    out[((size_t)(b*HH + th0 + ty)*WW + (tw0 + tx))*2 + n] = s;
  }
}

extern "C" void kernel_launch(void* const* d_in, const int* in_sizes, int n_in,
                              void* d_out, int out_size, void* d_ws, size_t ws_size,
                              hipStream_t stream) {
  const float* prv = (const float*)d_in[0];
  const float* nxt = (const float*)d_in[1];
  const float* cw  = (const float*)d_in[2];
  const float* cb  = (const float*)d_in[3];

  // ws layout: cost f16 [0, 28311552) | prv_h [28311552, +37748736) | nxt_h [...]
  char* wsb = (char*)d_ws;
  __half* cost  = (__half*)wsb;
  __half* prv_h = (__half*)(wsb + 28311552);
  __half* nxt_h = (__half*)(wsb + 28311552 + 37748736);

  k_convert<<<dim3(4608, 1, 2), dim3(256), 0, stream>>>((const float4*)prv, (const float4*)nxt,
                                                        (uint2*)prv_h, (uint2*)nxt_h);
  k_cost_mfma<<<dim3(6, 24, 16), dim3(512), 0, stream>>>((const uint4*)prv_h, (const uint4*)nxt_h, cost);
  k_conv_gemm<<<dim3(6, 6, 16), dim3(512), 0, stream>>>(prv_h, nxt_h, cost, cw, cb, (float*)d_out);
}